// Round 1
// baseline (1148.117 us; speedup 1.0000x reference)
//
#include <hip/hip_runtime.h>

#define BLOCK 256
#define R 8
#define OUT_TILE (BLOCK * R)      // 2048 outputs per block
#define KLEN 4096
#define NGROUPS 1536              // float4 groups of x-tile: (2048 + 4095) -> 6144 floats
#define NBODY (KLEN / 16)         // 256 bodies, 16 taps each

__device__ __forceinline__ void taps4(float acc[R], const float4 a, const float4 b,
                                      const float4 c, const float4 wv) {
    const float xv[12] = {a.x, a.y, a.z, a.w, b.x, b.y, b.z, b.w, c.x, c.y, c.z, c.w};
    const float wl[4]  = {wv.x, wv.y, wv.z, wv.w};
#pragma unroll
    for (int u = 0; u < 4; ++u) {
#pragma unroll
        for (int j = 0; j < R; ++j) {
            acc[j] = fmaf(xv[u + j], wl[u], acc[j]);
        }
    }
}

__global__ __launch_bounds__(BLOCK) void fir4096(const float* __restrict__ x,
                                                 const float* __restrict__ w,
                                                 float* __restrict__ out,
                                                 const int out_size, const long long n) {
    // x tile de-interleaved: even float4-groups / odd float4-groups.
    // Read pattern per tap-chunk c: all lanes hit ONE array at consecutive
    // slots (lane-stride 16B) -> conflict-free, no swizzle math in the loop.
    __shared__ float4 xsE[NGROUPS / 2];   // 12 KB
    __shared__ float4 xsO[NGROUPS / 2];   // 12 KB
    __shared__ float4 ws[KLEN / 4];       // 16 KB  (40 KB total -> 4 blocks/CU)

    const int t = threadIdx.x;
    const long long base = (long long)blockIdx.x * OUT_TILE;

    // stage w (uniform across blocks, L2/L3-resident)
#pragma unroll
    for (int i = 0; i < KLEN / 4 / BLOCK; ++i) {
        ws[t + BLOCK * i] = ((const float4*)w)[t + BLOCK * i];
    }

    // stage x[base .. base+6143]
#pragma unroll
    for (int i = 0; i < NGROUPS / BLOCK; ++i) {
        const int g = t + BLOCK * i;
        const long long gx = base + 4LL * g;
        float4 v;
        if (gx + 4 <= n) {
            v = *(const float4*)(x + gx);
        } else {            // tail block only
            v.x = (gx + 0 < n) ? x[gx + 0] : 0.0f;
            v.y = (gx + 1 < n) ? x[gx + 1] : 0.0f;
            v.z = (gx + 2 < n) ? x[gx + 2] : 0.0f;
            v.w = (gx + 3 < n) ? x[gx + 3] : 0.0f;
        }
        if (g & 1) xsO[g >> 1] = v; else xsE[g >> 1] = v;
    }
    __syncthreads();

    float acc[R];
#pragma unroll
    for (int j = 0; j < R; ++j) acc[j] = 0.0f;

    // sliding window: thread t's outputs are base + 8t .. base + 8t + 7.
    // window groups for tap-chunk c: 2t+c (a), 2t+c+1 (b), 2t+c+2 (new).
    float4 a = xsE[t];
    float4 b = xsO[t];
    int idx = t;
    for (int cc = 0; cc < NBODY; ++cc) {
        const float4 c1 = xsE[idx + 1];
        taps4(acc, a, b, c1, ws[4 * cc + 0]);
        const float4 d1 = xsO[idx + 1];
        taps4(acc, b, c1, d1, ws[4 * cc + 1]);
        const float4 e1 = xsE[idx + 2];
        taps4(acc, c1, d1, e1, ws[4 * cc + 2]);
        const float4 f1 = xsO[idx + 2];
        taps4(acc, d1, e1, f1, ws[4 * cc + 3]);
        a = e1;
        b = f1;
        idx += 2;
    }

    const long long o = base + (long long)t * R;
    if (o + R <= (long long)out_size) {
        *(float4*)(out + o)     = make_float4(acc[0], acc[1], acc[2], acc[3]);
        *(float4*)(out + o + 4) = make_float4(acc[4], acc[5], acc[6], acc[7]);
    } else {
#pragma unroll
        for (int j = 0; j < R; ++j) {
            if (o + j < (long long)out_size) out[o + j] = acc[j];
        }
    }
}

extern "C" void kernel_launch(void* const* d_in, const int* in_sizes, int n_in,
                              void* d_out, int out_size, void* d_ws, size_t ws_size,
                              hipStream_t stream) {
    const float* x  = (const float*)d_in[0];
    const float* w  = (const float*)d_in[1];
    float* out      = (float*)d_out;
    const long long n = in_sizes[0];
    const int nblocks = (out_size + OUT_TILE - 1) / OUT_TILE;
    fir4096<<<nblocks, BLOCK, 0, stream>>>(x, w, out, out_size, n);
}

// Round 6
// 998.801 us; speedup vs baseline: 1.1495x; 1.1495x over previous
//
#include <hip/hip_runtime.h>

#define BLOCK 256
#define R 8
#define OUT_TILE (BLOCK * R)        // 2048 outputs per block
#define KLEN 4096
#define XTILE (OUT_TILE + KLEN)     // 6144 floats staged (6143 needed + 1 spare)
#define PLANE (XTILE / 8)           // 768 slots per dword-plane
#define NC (KLEN / 8)               // 512 unrolled 8-tap groups

__global__ __launch_bounds__(BLOCK) void fir4096(const float* __restrict__ x,
                                                 const float* __restrict__ w,
                                                 float* __restrict__ out,
                                                 const int out_size, const long long n) {
    // x tile de-interleaved into 8 dword planes: x[base + 8s + d] -> xT[d][s].
    // Inner-loop reads hit ONE plane at lane-stride 4B -> bank = slot%32,
    // 2-way over 64 lanes = conflict-free. Plane base is a ds_read imm offset.
    __shared__ float xT[8][PLANE];    // 24 KB
    __shared__ float4 ws[KLEN / 4];   // 16 KB  (40 KB total -> 4 blocks/CU)

    const int t = threadIdx.x;
    const long long base = (long long)blockIdx.x * OUT_TILE;

    // stage w (uniform across blocks, L2/L3-resident)
#pragma unroll
    for (int i = 0; i < KLEN / 4 / BLOCK; ++i)
        ws[t + BLOCK * i] = ((const float4*)w)[t + BLOCK * i];

    // stage x[base .. base+6143], deinterleaving by dword position
    if (base + XTILE <= n) {
#pragma unroll
        for (int i = 0; i < XTILE / 8 / BLOCK; ++i) {   // 3 iterations
            const int g = t + BLOCK * i;                 // plane slot
            const float4 v0 = *(const float4*)(x + base + 8LL * g);
            const float4 v1 = *(const float4*)(x + base + 8LL * g + 4);
            xT[0][g] = v0.x; xT[1][g] = v0.y; xT[2][g] = v0.z; xT[3][g] = v0.w;
            xT[4][g] = v1.x; xT[5][g] = v1.y; xT[6][g] = v1.z; xT[7][g] = v1.w;
        }
    } else {                                             // tail block only
#pragma unroll
        for (int i = 0; i < XTILE / 8 / BLOCK; ++i) {
            const int g = t + BLOCK * i;
#pragma unroll
            for (int d = 0; d < 8; ++d) {
                const long long gx = base + 8LL * g + d;
                xT[d][g] = (gx < n) ? x[gx] : 0.0f;
            }
        }
    }
    __syncthreads();

    float acc[R];
#pragma unroll
    for (int j = 0; j < R; ++j) acc[j] = 0.0f;

    // register window: win[(k+j)&7] == x[8t + k + j] at tap k
    float win[8];
#pragma unroll
    for (int d = 0; d < 8; ++d) win[d] = xT[d][t];

    for (int c = 0; c < NC; ++c) {
        const float4 w0 = ws[2 * c + 0];                 // broadcast (free)
        const float4 w1 = ws[2 * c + 1];
        const float wl[8] = {w0.x, w0.y, w0.z, w0.w, w1.x, w1.y, w1.z, w1.w};
        const int slot = t + c + 1;
#pragma unroll
        for (int kk = 0; kk < 8; ++kk) {                 // tap k = 8c + kk
#pragma unroll
            for (int j = 0; j < R; ++j)
                acc[j] = fmaf(win[(kk + j) & 7], wl[kk], acc[j]);
            win[kk] = xT[kk][slot];                      // x[8t + 8c + kk + 8]
        }
    }

    const long long o = base + (long long)t * R;
    if (o + R <= (long long)out_size) {
        *(float4*)(out + o)     = make_float4(acc[0], acc[1], acc[2], acc[3]);
        *(float4*)(out + o + 4) = make_float4(acc[4], acc[5], acc[6], acc[7]);
    } else {
#pragma unroll
        for (int j = 0; j < R; ++j)
            if (o + j < (long long)out_size) out[o + j] = acc[j];
    }
}

extern "C" void kernel_launch(void* const* d_in, const int* in_sizes, int n_in,
                              void* d_out, int out_size, void* d_ws, size_t ws_size,
                              hipStream_t stream) {
    const float* x  = (const float*)d_in[0];
    const float* w  = (const float*)d_in[1];
    float* out      = (float*)d_out;
    const long long n = in_sizes[0];
    const int nblocks = (out_size + OUT_TILE - 1) / OUT_TILE;
    fir4096<<<nblocks, BLOCK, 0, stream>>>(x, w, out, out_size, n);
}

// Round 9
// 998.189 us; speedup vs baseline: 1.1502x; 1.0006x over previous
//
#include <hip/hip_runtime.h>

#define BLOCK 512
#define R 8
#define OUT_TILE (BLOCK * R)          // 4096 outputs per block
#define KLEN 4096
#define XTILE (OUT_TILE + KLEN)       // 8192 floats staged
#define PLANE 1026                    // 1024 used slots + 2 pad (dead final prefetch)
#define NW (KLEN / 4 + 2)             // 1024 float4 w entries + 2 pad
#define NITER (KLEN / 16)             // 256 double-group iterations (16 taps each)

__global__ __launch_bounds__(BLOCK) void fir4096(const float* __restrict__ x,
                                                 const float* __restrict__ w,
                                                 float* __restrict__ out,
                                                 const int out_size, const long long n) {
    // x tile as 8 dword planes: x[base + 8s + d] -> xT[d][s]; inner reads are
    // lane-stride-4B within one plane (plane base = imm offset) -> conflict-free.
    __shared__ float xT[8][PLANE];     // 32832 B
    __shared__ float4 wsv[NW];         // 16416 B  (49.2 KB -> 3 blocks/CU, 24 waves)

    const int t = threadIdx.x;
    const long long base = (long long)blockIdx.x * OUT_TILE;

    // stage w
#pragma unroll
    for (int i = 0; i < KLEN / 4 / BLOCK; ++i)            // 2 iters
        wsv[t + BLOCK * i] = ((const float4*)w)[t + BLOCK * i];

    // stage x[base .. base+8191], deinterleaved by dword position
    if (base + XTILE <= n) {
#pragma unroll
        for (int i = 0; i < XTILE / 8 / BLOCK; ++i) {     // 2 iters
            const int g = t + BLOCK * i;
            const float4 v0 = *(const float4*)(x + base + 8LL * g);
            const float4 v1 = *(const float4*)(x + base + 8LL * g + 4);
            xT[0][g] = v0.x; xT[1][g] = v0.y; xT[2][g] = v0.z; xT[3][g] = v0.w;
            xT[4][g] = v1.x; xT[5][g] = v1.y; xT[6][g] = v1.z; xT[7][g] = v1.w;
        }
    } else {                                              // tail block only
#pragma unroll
        for (int i = 0; i < XTILE / 8 / BLOCK; ++i) {
            const int g = t + BLOCK * i;
#pragma unroll
            for (int d = 0; d < 8; ++d) {
                const long long gx = base + 8LL * g + d;
                xT[d][g] = (gx < n) ? x[gx] : 0.0f;
            }
        }
    }
    __syncthreads();

    float acc[R];
#pragma unroll
    for (int j = 0; j < R; ++j) acc[j] = 0.0f;

    // window: a = x[o+16c .. +7], b = x[o+16c+8 .. +15]  (o = base + 8t)
    float a[8], b[8];
#pragma unroll
    for (int d = 0; d < 8; ++d) { a[d] = xT[d][t]; b[d] = xT[d][t + 1]; }
    float4 qa = wsv[0], qb = wsv[1];   // w[0..7] for group 0

    // 8 taps using LO/HI; refill dying LO[kk] with the group-after-next's
    // values -> every LDS load has an 8-tap (~128cy) source reuse distance.
#define GROUP8(LO, HI, SLOT, WA, WB)                                           \
    {                                                                           \
        const float wl[8] = {WA.x, WA.y, WA.z, WA.w, WB.x, WB.y, WB.z, WB.w};   \
        _Pragma("unroll")                                                       \
        for (int kk = 0; kk < 8; ++kk) {                                        \
            _Pragma("unroll")                                                   \
            for (int j = 0; j < R; ++j) {                                       \
                const int idx = kk + j;                                         \
                acc[j] = fmaf(idx < 8 ? LO[idx] : HI[idx - 8], wl[kk], acc[j]); \
            }                                                                   \
            LO[kk] = xT[kk][SLOT];                                              \
        }                                                                       \
    }

    for (int cc = 0; cc < NITER; ++cc) {
        const float4 qc = wsv[4 * cc + 2];                // w for odd group, one group early
        const float4 qd = wsv[4 * cc + 3];
        GROUP8(a, b, t + 2 * cc + 2, qa, qb);             // taps 16cc .. 16cc+7
        qa = wsv[4 * cc + 4];                             // w for next even group, one group early
        qb = wsv[4 * cc + 5];                             // (final iter reads pad entries - dead)
        GROUP8(b, a, t + 2 * cc + 3, qc, qd);             // taps 16cc+8 .. 16cc+15
    }
#undef GROUP8

    const long long o = base + (long long)t * R;
    if (o + R <= (long long)out_size) {
        *(float4*)(out + o)     = make_float4(acc[0], acc[1], acc[2], acc[3]);
        *(float4*)(out + o + 4) = make_float4(acc[4], acc[5], acc[6], acc[7]);
    } else {
#pragma unroll
        for (int j = 0; j < R; ++j)
            if (o + j < (long long)out_size) out[o + j] = acc[j];
    }
}

extern "C" void kernel_launch(void* const* d_in, const int* in_sizes, int n_in,
                              void* d_out, int out_size, void* d_ws, size_t ws_size,
                              hipStream_t stream) {
    const float* x  = (const float*)d_in[0];
    const float* w  = (const float*)d_in[1];
    float* out      = (float*)d_out;
    const long long n = in_sizes[0];
    const int nblocks = (out_size + OUT_TILE - 1) / OUT_TILE;
    fir4096<<<nblocks, BLOCK, 0, stream>>>(x, w, out, out_size, n);
}

// Round 11
// 728.998 us; speedup vs baseline: 1.5749x; 1.3693x over previous
//
#include <hip/hip_runtime.h>

#define BLOCK 256
#define R 16
#define OUT_TILE (BLOCK * R)          // 4096 outputs per block
#define KLEN 4096
#define XTILE (OUT_TILE + KLEN)       // 8192 floats staged
#define PSLOTS 520                    // 512 used slots + pad (dead final refills hit 512)
#define NITER (KLEN / 32)             // 128 iterations x 4 groups x 8 taps

__global__ __launch_bounds__(BLOCK) void fir4096(const float* __restrict__ x,
                                                 const float* __restrict__ w,
                                                 float* __restrict__ out,
                                                 const int out_size, const long long n) {
    // x tile as 16 dword planes: x[base+16s+d] -> xT[d][s]. Refills read ONE
    // plane at lane-stride 4B (slot = t+const) -> 2-way aliasing = free.
    // w is NOT in LDS: wave-uniform global reads (SMEM/L1 broadcast path),
    // keeping the DS pipe exclusively for x refills.
    __shared__ float xT[16][PSLOTS];   // 33280 B -> 4 blocks/CU, 16 waves

    const int t = threadIdx.x;
    const long long base = (long long)blockIdx.x * OUT_TILE;

    if (base + XTILE <= n) {
#pragma unroll
        for (int it = 0; it < XTILE / 16 / BLOCK; ++it) {   // 2 iters
            const int s = t + BLOCK * it;
#pragma unroll
            for (int q = 0; q < 4; ++q) {
                const float4 v = *(const float4*)(x + base + 16LL * s + 4 * q);
                xT[4 * q + 0][s] = v.x; xT[4 * q + 1][s] = v.y;
                xT[4 * q + 2][s] = v.z; xT[4 * q + 3][s] = v.w;
            }
        }
    } else {                                                 // tail block only
#pragma unroll
        for (int it = 0; it < XTILE / 16 / BLOCK; ++it) {
            const int s = t + BLOCK * it;
#pragma unroll
            for (int d = 0; d < 16; ++d) {
                const long long gx = base + 16LL * s + d;
                xT[d][s] = (gx < n) ? x[gx] : 0.0f;
            }
        }
    }
    __syncthreads();

    float acc[R];
#pragma unroll
    for (int j = 0; j < R; ++j) acc[j] = 0.0f;

    // window banks: A,B,C,D = x[o .. o+31], o = base + 16t
    float A[8], Bv[8], Cv[8], Dv[8];
#pragma unroll
    for (int d = 0; d < 8; ++d) {
        A[d]  = xT[d][t];      Bv[d] = xT[8 + d][t];
        Cv[d] = xT[d][t + 1];  Dv[d] = xT[8 + d][t + 1];
    }

    const float4* wq = (const float4*)w;
    float4 qa = wq[0], qb = wq[1];                 // w[0..7] for group 0

    // 8 taps over banks B0,B1,B2 (23 live values); refill dying B0[kk] with
    // data consumed 2 groups later (~500cy reuse distance).
#define GROUP8(B0, B1, B2, PB, SLOT, WA, WB)                                   \
    {                                                                           \
        const float wl[8] = {WA.x, WA.y, WA.z, WA.w, WB.x, WB.y, WB.z, WB.w};   \
        _Pragma("unroll")                                                       \
        for (int kk = 0; kk < 8; ++kk) {                                        \
            _Pragma("unroll")                                                   \
            for (int j = 0; j < R; ++j) {                                       \
                const int idx = kk + j;                                         \
                const float xv = idx < 8 ? B0[idx]                              \
                               : (idx < 16 ? B1[idx - 8] : B2[idx - 16]);       \
                acc[j] = fmaf(xv, wl[kk], acc[j]);                              \
            }                                                                   \
            B0[kk] = xT[(PB) + kk][SLOT];                                       \
        }                                                                       \
    }

    for (int m = 0; m < NITER; ++m) {
        const int s0 = t + 2 * m + 2;
        const float4 qc = wq[8 * m + 2], qd = wq[8 * m + 3];   // group 4m+1 w
        GROUP8(A,  Bv, Cv, 0, s0,     qa, qb);                 // taps 32m+0..7
        const float4 qe = wq[8 * m + 4], qf = wq[8 * m + 5];   // group 4m+2 w
        GROUP8(Bv, Cv, Dv, 8, s0,     qc, qd);                 // taps 32m+8..15
        const float4 qg = wq[8 * m + 6], qh = wq[8 * m + 7];   // group 4m+3 w
        GROUP8(Cv, Dv, A,  0, s0 + 1, qe, qf);                 // taps 32m+16..23
        const int nx = (m == NITER - 1) ? 0 : 8 * m + 8;       // clamp dead prefetch
        qa = wq[nx]; qb = wq[nx + 1];                          // next iter group-0 w
        GROUP8(Dv, A,  Bv, 8, s0 + 1, qg, qh);                 // taps 32m+24..31
    }
#undef GROUP8

    const long long o = base + (long long)t * R;
    if (o + R <= (long long)out_size) {
        *(float4*)(out + o)      = make_float4(acc[0],  acc[1],  acc[2],  acc[3]);
        *(float4*)(out + o + 4)  = make_float4(acc[4],  acc[5],  acc[6],  acc[7]);
        *(float4*)(out + o + 8)  = make_float4(acc[8],  acc[9],  acc[10], acc[11]);
        *(float4*)(out + o + 12) = make_float4(acc[12], acc[13], acc[14], acc[15]);
    } else {
#pragma unroll
        for (int j = 0; j < R; ++j)
            if (o + j < (long long)out_size) out[o + j] = acc[j];
    }
}

extern "C" void kernel_launch(void* const* d_in, const int* in_sizes, int n_in,
                              void* d_out, int out_size, void* d_ws, size_t ws_size,
                              hipStream_t stream) {
    const float* x  = (const float*)d_in[0];
    const float* w  = (const float*)d_in[1];
    float* out      = (float*)d_out;
    const long long n = in_sizes[0];
    const int nblocks = (out_size + OUT_TILE - 1) / OUT_TILE;
    fir4096<<<nblocks, BLOCK, 0, stream>>>(x, w, out, out_size, n);
}

// Round 13
// 287.506 us; speedup vs baseline: 3.9934x; 2.5356x over previous
//
#include <hip/hip_runtime.h>

typedef __attribute__((ext_vector_type(8))) short bf16x8;
typedef __attribute__((ext_vector_type(16))) float f32x16;

#define KLEN 4096
#define JPAD 16
#define NTAB 288          // padded w-fragment table entries (j' in [-16, 272))
#define NJ 272            // main-loop global steps
#define MBLK 8192         // outputs per block = 8 tiles x 1024
#define XWIN 12288        // x window elements per block

__device__ __forceinline__ ushort f2bf(float f) {      // RNE fp32->bf16
    uint u = __float_as_uint(f);
    u += 0x7fff + ((u >> 16) & 1);
    return (ushort)(u >> 16);
}
__device__ __forceinline__ float bf2f(ushort h) { return __uint_as_float(((uint)h) << 16); }
__device__ __forceinline__ int swz(int v) { return v ^ ((v >> 6) & 15); }  // 8B-unit swizzle

// A-fragment table: A_{j'}[r][kap] = w[16j' + kap - r], lane l: r=l&31, kap=(l>>5)*8+e.
// wtab[j][l] = 8 bf16 (hi), wtab[NTAB*64 + j][l] = lo.  Zero outside k in [0,4096).
__global__ void build_wtab(const float* __restrict__ w, uint4* __restrict__ wtab) {
    const int j = blockIdx.x;          // 0..287, jr = j-16
    const int l = threadIdx.x;         // 0..63
    const int jr = j - JPAD;
    const int r = l & 31, hb = l >> 5;
    uint hp[4], lp[4];
#pragma unroll
    for (int i = 0; i < 4; ++i) {
        ushort h2[2], l2[2];
#pragma unroll
        for (int s = 0; s < 2; ++s) {
            const int e = 2 * i + s;
            const int k = 16 * jr + hb * 8 + e - r;
            const float v = (k >= 0 && k < KLEN) ? w[k] : 0.0f;
            h2[s] = f2bf(v);
            l2[s] = f2bf(v - bf2f(h2[s]));
        }
        hp[i] = (uint)h2[0] | ((uint)h2[1] << 16);
        lp[i] = (uint)l2[0] | ((uint)l2[1] << 16);
    }
    wtab[j * 64 + l]             = make_uint4(hp[0], hp[1], hp[2], hp[3]);
    wtab[NTAB * 64 + j * 64 + l] = make_uint4(lp[0], lp[1], lp[2], lp[3]);
}

__global__ __launch_bounds__(256, 3) void fir_mfma(const float* __restrict__ x,
                                                   const uint4* __restrict__ wtab,
                                                   float* __restrict__ out,
                                                   const int out_size, const long long n) {
    __shared__ __align__(16) ushort xh[XWIN];
    __shared__ __align__(16) ushort xl[XWIN];
    const int t = threadIdx.x;
    const long long i0 = (long long)blockIdx.x * MBLK;

    // ---- stage x window as bf16 hi/lo, swizzled 8B units ----
#pragma unroll
    for (int it = 0; it < XWIN / 8 / 256; ++it) {        // 6 iters
        const int s = 8 * (t + 256 * it);
        const long long g = i0 + s;
        float v[8];
        if (g + 8 <= n) {
            const float4 A = *(const float4*)(x + g);
            const float4 B = *(const float4*)(x + g + 4);
            v[0] = A.x; v[1] = A.y; v[2] = A.z; v[3] = A.w;
            v[4] = B.x; v[5] = B.y; v[6] = B.z; v[7] = B.w;
        } else {
#pragma unroll
            for (int e = 0; e < 8; ++e) v[e] = (g + e < n) ? x[g + e] : 0.0f;
        }
        uint hp[4], lp[4];
#pragma unroll
        for (int i = 0; i < 4; ++i) {
            const ushort h0 = f2bf(v[2 * i]),     h1 = f2bf(v[2 * i + 1]);
            const ushort l0 = f2bf(v[2 * i] - bf2f(h0));
            const ushort l1 = f2bf(v[2 * i + 1] - bf2f(h1));
            hp[i] = (uint)h0 | ((uint)h1 << 16);
            lp[i] = (uint)l0 | ((uint)l1 << 16);
        }
        const int v0 = s >> 2;
        *(uint2*)(xh + swz(v0) * 4)     = make_uint2(hp[0], hp[1]);
        *(uint2*)(xh + swz(v0 + 1) * 4) = make_uint2(hp[2], hp[3]);
        *(uint2*)(xl + swz(v0) * 4)     = make_uint2(lp[0], lp[1]);
        *(uint2*)(xl + swz(v0 + 1) * 4) = make_uint2(lp[2], lp[3]);
    }
    __syncthreads();

    // ---- MFMA main loop: wave wv owns tiles m = 2wv, 2wv+1 ----
    const int l = t & 63, wv = t >> 6;
    const int c = l & 31, hb = l >> 5;
    f32x16 acc0 = (f32x16)(0.0f);
    f32x16 acc1 = (f32x16)(0.0f);
    const uint4* wtH = wtab;
    const uint4* wtL = wtab + NTAB * 64;

    for (int j = 0; j < NJ; ++j) {
        // B_j: x[i0 + 16j + (hb*8+e) + 256c], e=0..7  (two swizzled ds_read_b64 each)
        const int v0 = 4 * j + 2 * hb + 64 * c;
        const uint2 bh0 = *(const uint2*)(xh + swz(v0) * 4);
        const uint2 bh1 = *(const uint2*)(xh + swz(v0 + 1) * 4);
        const uint2 bl0 = *(const uint2*)(xl + swz(v0) * 4);
        const uint2 bl1 = *(const uint2*)(xl + swz(v0 + 1) * 4);
        union { uint4 u; bf16x8 s; } Bh, Bl, Ah0, Al0, Ah1, Al1;
        Bh.u = make_uint4(bh0.x, bh0.y, bh1.x, bh1.y);
        Bl.u = make_uint4(bl0.x, bl0.y, bl1.x, bl1.y);
        // A_{j-2m}: tile0 jj = j-4wv+JPAD, tile1 jj-2 (padded table, zeros outside)
        const int jA = j - 4 * wv + JPAD;
        const int jB = jA - 2;
        Ah0.u = wtH[jA * 64 + l];  Al0.u = wtL[jA * 64 + l];
        Ah1.u = wtH[jB * 64 + l];  Al1.u = wtL[jB * 64 + l];
        acc0 = __builtin_amdgcn_mfma_f32_32x32x16_bf16(Ah0.s, Bh.s, acc0, 0, 0, 0);
        acc1 = __builtin_amdgcn_mfma_f32_32x32x16_bf16(Ah1.s, Bh.s, acc1, 0, 0, 0);
        acc0 = __builtin_amdgcn_mfma_f32_32x32x16_bf16(Al0.s, Bh.s, acc0, 0, 0, 0);
        acc1 = __builtin_amdgcn_mfma_f32_32x32x16_bf16(Al1.s, Bh.s, acc1, 0, 0, 0);
        acc0 = __builtin_amdgcn_mfma_f32_32x32x16_bf16(Ah0.s, Bl.s, acc0, 0, 0, 0);
        acc1 = __builtin_amdgcn_mfma_f32_32x32x16_bf16(Ah1.s, Bl.s, acc1, 0, 0, 0);
    }

    // ---- store: D row=(reg&3)+8*(reg>>2)+4*hb, col=c; out = i0_t + row + 256*col ----
    const long long tb0 = i0 + 32LL * (2 * wv);
    const long long tb1 = tb0 + 32;
#pragma unroll
    for (int q = 0; q < 4; ++q) {
        const long long o0 = tb0 + 8 * q + 4 * hb + 256 * c;
        if (o0 + 4 <= (long long)out_size) {
            *(float4*)(out + o0) = make_float4(acc0[4*q], acc0[4*q+1], acc0[4*q+2], acc0[4*q+3]);
        } else {
#pragma unroll
            for (int d = 0; d < 4; ++d)
                if (o0 + d < (long long)out_size) out[o0 + d] = acc0[4*q + d];
        }
        const long long o1 = tb1 + 8 * q + 4 * hb + 256 * c;
        if (o1 + 4 <= (long long)out_size) {
            *(float4*)(out + o1) = make_float4(acc1[4*q], acc1[4*q+1], acc1[4*q+2], acc1[4*q+3]);
        } else {
#pragma unroll
            for (int d = 0; d < 4; ++d)
                if (o1 + d < (long long)out_size) out[o1 + d] = acc1[4*q + d];
        }
    }
}

extern "C" void kernel_launch(void* const* d_in, const int* in_sizes, int n_in,
                              void* d_out, int out_size, void* d_ws, size_t ws_size,
                              hipStream_t stream) {
    const float* x = (const float*)d_in[0];
    const float* w = (const float*)d_in[1];
    float* out     = (float*)d_out;
    const long long n = in_sizes[0];
    uint4* wtab = (uint4*)d_ws;                       // needs 2*288*64*16 = 589824 B
    build_wtab<<<NTAB, 64, 0, stream>>>(w, wtab);
    const int nblocks = (out_size + MBLK - 1) / MBLK; // 1024
    fir_mfma<<<nblocks, 256, 0, stream>>>(x, wtab, out, out_size, n);
}

// Round 14
// 260.481 us; speedup vs baseline: 4.4077x; 1.1037x over previous
//
#include <hip/hip_runtime.h>

typedef __attribute__((ext_vector_type(8))) short bf16x8;
typedef __attribute__((ext_vector_type(16))) float f32x16;

#define KLEN 4096
#define JPAD 16
#define NTAB 292          // padded w-fragment table (j' in [-16, 276)); pad covers dead prefetch
#define NJ 272            // main-loop global steps
#define MBLK 8192         // outputs per block = 8 tiles x 1024
#define XWIN 12288        // x window elements per block

__device__ __forceinline__ ushort f2bf(float f) {      // RNE fp32->bf16
    uint u = __float_as_uint(f);
    u += 0x7fff + ((u >> 16) & 1);
    return (ushort)(u >> 16);
}
__device__ __forceinline__ float bf2f(ushort h) { return __uint_as_float(((uint)h) << 16); }
__device__ __forceinline__ int swz(int v) { return v ^ ((v >> 6) & 15); }  // 8B-unit swizzle

// A-fragment table: A_{j'}[r][kap] = w[16j' + kap - r], lane l: r=l&31, kap=(l>>5)*8+e.
__global__ void build_wtab(const float* __restrict__ w, uint4* __restrict__ wtab) {
    const int j = blockIdx.x;          // 0..NTAB-1, jr = j-16
    const int l = threadIdx.x;         // 0..63
    const int jr = j - JPAD;
    const int r = l & 31, hb = l >> 5;
    uint hp[4], lp[4];
#pragma unroll
    for (int i = 0; i < 4; ++i) {
        ushort h2[2], l2[2];
#pragma unroll
        for (int s = 0; s < 2; ++s) {
            const int e = 2 * i + s;
            const int k = 16 * jr + hb * 8 + e - r;
            const float v = (k >= 0 && k < KLEN) ? w[k] : 0.0f;
            h2[s] = f2bf(v);
            l2[s] = f2bf(v - bf2f(h2[s]));
        }
        hp[i] = (uint)h2[0] | ((uint)h2[1] << 16);
        lp[i] = (uint)l2[0] | ((uint)l2[1] << 16);
    }
    wtab[j * 64 + l]             = make_uint4(hp[0], hp[1], hp[2], hp[3]);
    wtab[NTAB * 64 + j * 64 + l] = make_uint4(lp[0], lp[1], lp[2], lp[3]);
}

__global__ __launch_bounds__(256, 3) void fir_mfma(const float* __restrict__ x,
                                                   const uint4* __restrict__ wtab,
                                                   float* __restrict__ out,
                                                   const int out_size, const long long n) {
    __shared__ __align__(16) ushort xh[XWIN];
    __shared__ __align__(16) ushort xl[XWIN];
    const int t = threadIdx.x;
    const long long i0 = (long long)blockIdx.x * MBLK;

    // ---- stage x window as bf16 hi/lo, swizzled 8B units ----
#pragma unroll
    for (int it = 0; it < XWIN / 8 / 256; ++it) {        // 6 iters
        const int s = 8 * (t + 256 * it);
        const long long g = i0 + s;
        float v[8];
        if (g + 8 <= n) {
            const float4 A = *(const float4*)(x + g);
            const float4 B = *(const float4*)(x + g + 4);
            v[0] = A.x; v[1] = A.y; v[2] = A.z; v[3] = A.w;
            v[4] = B.x; v[5] = B.y; v[6] = B.z; v[7] = B.w;
        } else {
#pragma unroll
            for (int e = 0; e < 8; ++e) v[e] = (g + e < n) ? x[g + e] : 0.0f;
        }
        uint hp[4], lp[4];
#pragma unroll
        for (int i = 0; i < 4; ++i) {
            const ushort h0 = f2bf(v[2 * i]),     h1 = f2bf(v[2 * i + 1]);
            const ushort l0 = f2bf(v[2 * i] - bf2f(h0));
            const ushort l1 = f2bf(v[2 * i + 1] - bf2f(h1));
            hp[i] = (uint)h0 | ((uint)h1 << 16);
            lp[i] = (uint)l0 | ((uint)l1 << 16);
        }
        const int v0 = s >> 2;
        *(uint2*)(xh + swz(v0) * 4)     = make_uint2(hp[0], hp[1]);
        *(uint2*)(xh + swz(v0 + 1) * 4) = make_uint2(hp[2], hp[3]);
        *(uint2*)(xl + swz(v0) * 4)     = make_uint2(lp[0], lp[1]);
        *(uint2*)(xl + swz(v0 + 1) * 4) = make_uint2(lp[2], lp[3]);
    }
    __syncthreads();

    // ---- MFMA main loop: wave wv owns tiles m = 2wv, 2wv+1 ----
    const int l = t & 63, wv = t >> 6;
    const int c = l & 31, hb = l >> 5;
    f32x16 acc0 = (f32x16)(0.0f);
    f32x16 acc1 = (f32x16)(0.0f);
    const uint4* wtH = wtab;
    const uint4* wtL = wtab + NTAB * 64;

    typedef union { uint4 u; bf16x8 s; } frag;
    frag AH[4], AL[4], BH[2], BL[2];
    const int e0 = JPAD - 4 * wv;                        // tile0 entry at j=0 (>= 4)

#define LOADA(SLOT, E)                                                        \
    { AH[SLOT].u = wtH[(E) * 64 + l]; AL[SLOT].u = wtL[(E) * 64 + l]; }
#define LOADB(SLOT, J)                                                        \
    { const int v0 = 4 * (J) + 2 * hb + 64 * c;                               \
      const uint2 h0 = *(const uint2*)(xh + swz(v0) * 4);                     \
      const uint2 h1 = *(const uint2*)(xh + swz(v0 + 1) * 4);                 \
      const uint2 l0 = *(const uint2*)(xl + swz(v0) * 4);                     \
      const uint2 l1 = *(const uint2*)(xl + swz(v0 + 1) * 4);                 \
      BH[SLOT].u = make_uint4(h0.x, h0.y, h1.x, h1.y);                        \
      BL[SLOT].u = make_uint4(l0.x, l0.y, l1.x, l1.y); }

    // prologue: A slots {0: e0, 2: e0-2, 3: e0-1}; B slot 0 = step 0
    LOADA(0, e0); LOADA(2, e0 - 2); LOADA(3, e0 - 1);
    LOADB(0, 0);

    // sub-step u (j = 4m+u): prefetch A(e0+j+1) -> slot (u+1)&3, B(j+1) -> slot (u+1)&1;
    // tile0 uses A slot u (= entry e0+j), tile1 uses slot (u+2)&3 (= entry e0+j-2).
#define SUBSTEP(u, m)                                                          \
    { const int j = 4 * (m) + (u);                                             \
      LOADA(((u) + 1) & 3, e0 + j + 1);                                        \
      const int jp = ((u) == 3 && (m) == NJ / 4 - 1) ? j : j + 1;              \
      LOADB(((u) + 1) & 1, jp);                                                \
      acc0 = __builtin_amdgcn_mfma_f32_32x32x16_bf16(AH[(u)].s,           BH[(u) & 1].s, acc0, 0, 0, 0); \
      acc1 = __builtin_amdgcn_mfma_f32_32x32x16_bf16(AH[((u) + 2) & 3].s, BH[(u) & 1].s, acc1, 0, 0, 0); \
      acc0 = __builtin_amdgcn_mfma_f32_32x32x16_bf16(AL[(u)].s,           BH[(u) & 1].s, acc0, 0, 0, 0); \
      acc1 = __builtin_amdgcn_mfma_f32_32x32x16_bf16(AL[((u) + 2) & 3].s, BH[(u) & 1].s, acc1, 0, 0, 0); \
      acc0 = __builtin_amdgcn_mfma_f32_32x32x16_bf16(AH[(u)].s,           BL[(u) & 1].s, acc0, 0, 0, 0); \
      acc1 = __builtin_amdgcn_mfma_f32_32x32x16_bf16(AH[((u) + 2) & 3].s, BL[(u) & 1].s, acc1, 0, 0, 0); }

    for (int m = 0; m < NJ / 4; ++m) {
        SUBSTEP(0, m); SUBSTEP(1, m); SUBSTEP(2, m); SUBSTEP(3, m);
    }
#undef SUBSTEP
#undef LOADB
#undef LOADA

    // ---- store: D row=(reg&3)+8*(reg>>2)+4*hb, col=c; out = tile_base + row + 256*col ----
    const long long tb0 = i0 + 32LL * (2 * wv);
    const long long tb1 = tb0 + 32;
#pragma unroll
    for (int q = 0; q < 4; ++q) {
        const long long o0 = tb0 + 8 * q + 4 * hb + 256 * c;
        if (o0 + 4 <= (long long)out_size) {
            *(float4*)(out + o0) = make_float4(acc0[4*q], acc0[4*q+1], acc0[4*q+2], acc0[4*q+3]);
        } else {
#pragma unroll
            for (int d = 0; d < 4; ++d)
                if (o0 + d < (long long)out_size) out[o0 + d] = acc0[4*q + d];
        }
        const long long o1 = tb1 + 8 * q + 4 * hb + 256 * c;
        if (o1 + 4 <= (long long)out_size) {
            *(float4*)(out + o1) = make_float4(acc1[4*q], acc1[4*q+1], acc1[4*q+2], acc1[4*q+3]);
        } else {
#pragma unroll
            for (int d = 0; d < 4; ++d)
                if (o1 + d < (long long)out_size) out[o1 + d] = acc1[4*q + d];
        }
    }
}

extern "C" void kernel_launch(void* const* d_in, const int* in_sizes, int n_in,
                              void* d_out, int out_size, void* d_ws, size_t ws_size,
                              hipStream_t stream) {
    const float* x = (const float*)d_in[0];
    const float* w = (const float*)d_in[1];
    float* out     = (float*)d_out;
    const long long n = in_sizes[0];
    uint4* wtab = (uint4*)d_ws;                       // needs 2*292*64*16 = 598016 B
    build_wtab<<<NTAB, 64, 0, stream>>>(w, wtab);
    const int nblocks = (out_size + MBLK - 1) / MBLK; // 1024
    fir_mfma<<<nblocks, 256, 0, stream>>>(x, wtab, out, out_size, n);
}

// Round 16
// 234.462 us; speedup vs baseline: 4.8968x; 1.1110x over previous
//
#include <hip/hip_runtime.h>

typedef __attribute__((ext_vector_type(8))) short bf16x8;
typedef __attribute__((ext_vector_type(16))) float f32x16;

#define KLEN 4096
#define JPAD 30           // table offset: covers entry e0w-6 = JPAD-8*3-6 = 0
#define NTAB 320          // JPAD + NJ + prefetch pad (max access 318)
#define NJ 288            // global steps: j' in [0,258) nonzero, + 2*m up to 30
#define MBLK 16384        // outputs per block = 16 tiles x 1024 (col-stride 512)
#define XWIN 20480        // x window elements per block (max idx 20479)
#define XUNITS (XWIN / 8) // 16B units per LDS array

__device__ __forceinline__ ushort f2bf(float f) {      // RNE fp32->bf16
    uint u = __float_as_uint(f);
    u += 0x7fff + ((u >> 16) & 1);
    return (ushort)(u >> 16);
}
__device__ __forceinline__ float bf2f(ushort h) { return __uint_as_float(((uint)h) << 16); }
__device__ __forceinline__ int swz(int p) { return p ^ ((p >> 6) & 15); }  // 16B-unit swizzle

// A-fragment table: A_{j'}[r][kap] = w[16j' + kap - r]; lane l: r=l&31, kap=(l>>5)*8+e.
__global__ void build_wtab(const float* __restrict__ w, uint4* __restrict__ wtab) {
    const int j = blockIdx.x;          // 0..NTAB-1, jr = j - JPAD
    const int l = threadIdx.x;         // 0..63
    const int jr = j - JPAD;
    const int r = l & 31, hb = l >> 5;
    uint hp[4], lp[4];
#pragma unroll
    for (int i = 0; i < 4; ++i) {
        ushort h2[2], l2[2];
#pragma unroll
        for (int s = 0; s < 2; ++s) {
            const int e = 2 * i + s;
            const int k = 16 * jr + hb * 8 + e - r;
            const float v = (k >= 0 && k < KLEN) ? w[k] : 0.0f;
            h2[s] = f2bf(v);
            l2[s] = f2bf(v - bf2f(h2[s]));
        }
        hp[i] = (uint)h2[0] | ((uint)h2[1] << 16);
        lp[i] = (uint)l2[0] | ((uint)l2[1] << 16);
    }
    wtab[j * 64 + l]             = make_uint4(hp[0], hp[1], hp[2], hp[3]);
    wtab[NTAB * 64 + j * 64 + l] = make_uint4(lp[0], lp[1], lp[2], lp[3]);
}

__global__ __launch_bounds__(256, 2) void fir_mfma(const float* __restrict__ x,
                                                   const uint4* __restrict__ wtab,
                                                   float* __restrict__ out,
                                                   const int out_size, const long long n) {
    __shared__ __align__(16) ushort xh[XWIN];   // 40 KB
    __shared__ __align__(16) ushort xl[XWIN];   // 40 KB  (80 KB -> 2 blocks/CU)
    const int t = threadIdx.x;
    const long long i0 = (long long)blockIdx.x * MBLK;

    // ---- stage x window as bf16 hi/lo, 16B-unit swizzled ----
#pragma unroll
    for (int it = 0; it < XUNITS / 256; ++it) {          // 10 iters
        const int p = t + 256 * it;                      // 16B unit = 8 elems
        const long long g = i0 + 8LL * p;
        float v[8];
        if (g + 8 <= n) {
            const float4 A = *(const float4*)(x + g);
            const float4 B = *(const float4*)(x + g + 4);
            v[0] = A.x; v[1] = A.y; v[2] = A.z; v[3] = A.w;
            v[4] = B.x; v[5] = B.y; v[6] = B.z; v[7] = B.w;
        } else {
#pragma unroll
            for (int e = 0; e < 8; ++e) v[e] = (g + e < n) ? x[g + e] : 0.0f;
        }
        uint hp[4], lp[4];
#pragma unroll
        for (int i = 0; i < 4; ++i) {
            const ushort h0 = f2bf(v[2 * i]),     h1 = f2bf(v[2 * i + 1]);
            const ushort l0 = f2bf(v[2 * i] - bf2f(h0));
            const ushort l1 = f2bf(v[2 * i + 1] - bf2f(h1));
            hp[i] = (uint)h0 | ((uint)h1 << 16);
            lp[i] = (uint)l0 | ((uint)l1 << 16);
        }
        *(uint4*)(xh + swz(p) * 8) = make_uint4(hp[0], hp[1], hp[2], hp[3]);
        *(uint4*)(xl + swz(p) * 8) = make_uint4(lp[0], lp[1], lp[2], lp[3]);
    }
    __syncthreads();

    // ---- MFMA main loop: wave wv owns tiles m = 4wv + ta, ta = 0..3 ----
    const int l = t & 63, wv = t >> 6;
    const int c = l & 31, hb = l >> 5;
    const int e0w = JPAD - 8 * wv;                       // tile ta=0 entry at j=0
    f32x16 acc[4];
#pragma unroll
    for (int ta = 0; ta < 4; ++ta) acc[ta] = (f32x16)(0.0f);
    const uint4* wtH = wtab;
    const uint4* wtL = wtab + NTAB * 64;

    typedef union { uint4 u; bf16x8 s; } frag;
    frag AH[8], AL[8], BHf[2], BLf[2];

#define LOADA(S, E)                                                           \
    { AH[S].u = wtH[(E) * 64 + l]; AL[S].u = wtL[(E) * 64 + l]; }
#define LOADB(S, J)                                                           \
    { const int p = 2 * (J) + hb + 64 * c;                                    \
      BHf[S].u = *(const uint4*)(xh + swz(p) * 8);                            \
      BLf[S].u = *(const uint4*)(xl + swz(p) * 8); }

    // prologue: slot s holds entry E with (E - e0w) === s (mod 8), newest <= e0w
    LOADA(0, e0w);     LOADA(7, e0w - 1); LOADA(6, e0w - 2); LOADA(5, e0w - 3);
    LOADA(4, e0w - 4); LOADA(3, e0w - 5); LOADA(2, e0w - 6);
    LOADB(0, 0);

    // substep U (j = 8mm+U): prefetch A entry e0w+j+1 -> slot (U+1)&7,
    // B_{j+1} -> slot (U+1)&1; tile ta uses A slot (U-2ta)&7, B slot U&1.
    // Final substep clamps the dead B prefetch (j+1 = NJ would exceed XWIN).
#define SUBSTEP(U)                                                            \
    { const int j = 8 * mm + (U);                                             \
      LOADA(((U) + 1) & 7, e0w + j + 1);                                      \
      const int jp = ((U) == 7 && mm == NJ / 8 - 1) ? j : j + 1;              \
      LOADB(((U) + 1) & 1, jp);                                               \
      _Pragma("unroll")                                                       \
      for (int ta = 0; ta < 4; ++ta) {                                        \
          const int As = ((U) - 2 * ta) & 7;                                  \
          acc[ta] = __builtin_amdgcn_mfma_f32_32x32x16_bf16(AH[As].s, BHf[(U) & 1].s, acc[ta], 0, 0, 0); \
          acc[ta] = __builtin_amdgcn_mfma_f32_32x32x16_bf16(AL[As].s, BHf[(U) & 1].s, acc[ta], 0, 0, 0); \
          acc[ta] = __builtin_amdgcn_mfma_f32_32x32x16_bf16(AH[As].s, BLf[(U) & 1].s, acc[ta], 0, 0, 0); \
      } }

    for (int mm = 0; mm < NJ / 8; ++mm) {                // 36 iterations
        SUBSTEP(0) SUBSTEP(1) SUBSTEP(2) SUBSTEP(3)
        SUBSTEP(4) SUBSTEP(5) SUBSTEP(6) SUBSTEP(7)
    }
#undef SUBSTEP
#undef LOADB
#undef LOADA

    // ---- store: D row=(reg&3)+8*(reg>>2)+4*hb, col=c; out = tb + row + 512*col ----
#pragma unroll
    for (int ta = 0; ta < 4; ++ta) {
        const long long tb = i0 + 32LL * (4 * wv + ta);
#pragma unroll
        for (int q = 0; q < 4; ++q) {
            const long long o = tb + 8 * q + 4 * hb + 512 * c;
            if (o + 4 <= (long long)out_size) {
                *(float4*)(out + o) = make_float4(acc[ta][4*q], acc[ta][4*q+1],
                                                  acc[ta][4*q+2], acc[ta][4*q+3]);
            } else {
#pragma unroll
                for (int d = 0; d < 4; ++d)
                    if (o + d < (long long)out_size) out[o + d] = acc[ta][4*q + d];
            }
        }
    }
}

extern "C" void kernel_launch(void* const* d_in, const int* in_sizes, int n_in,
                              void* d_out, int out_size, void* d_ws, size_t ws_size,
                              hipStream_t stream) {
    const float* x = (const float*)d_in[0];
    const float* w = (const float*)d_in[1];
    float* out     = (float*)d_out;
    const long long n = in_sizes[0];
    uint4* wtab = (uint4*)d_ws;                       // needs 2*320*64*16 = 655360 B
    build_wtab<<<NTAB, 64, 0, stream>>>(w, wtab);
    const int nblocks = (out_size + MBLK - 1) / MBLK; // 512
    fir_mfma<<<nblocks, 256, 0, stream>>>(x, wtab, out, out_size, n);
}